// Round 6
// baseline (68.123 us; speedup 1.0000x reference)
//
#include <hip/hip_runtime.h>

#define EDIM 10
#define CDIM 128
#define DDIM 9
#define BDIM 512
#define NT3 165   // #(a<=b<=c) triples over 9 dims
#define NT2 45    // #(a<=b) pairs
#define NT1 9
#define NT 219
#define NENT (NT * 8)  // 1752 slice entries (t x 8 channels)

// ---------------------------------------------------------------------------
// Single fused kernel. Grid = 16 row-chunks x 16 channel-tiles = 256 blocks,
// 256 threads (= 8 channels x 32 row-slots, 4 waves of 8c x 8slots).
// Phases: (1) deterministic species sort via bitmask ranks (every block,
// redundant but order-independent); (2) LDS coefficient slice per species
// present in this block's 32 sorted rows; (3) 219-term polynomial from LDS.
// ---------------------------------------------------------------------------
__global__ __launch_bounds__(256) void symcon_one_kernel(
    const float* __restrict__ x, const float* __restrict__ y,
    const float* __restrict__ u1_0e, const float* __restrict__ w1_0e,
    const float* __restrict__ u2_0e, const float* __restrict__ w2_0e,
    const float* __restrict__ u3_0e, const float* __restrict__ w3_0e,
    const float* __restrict__ u1_1o, const float* __restrict__ w1_1o,
    const float* __restrict__ u2_1o, const float* __restrict__ w2_1o,
    const float* __restrict__ u3_1o, const float* __restrict__ w3_1o,
    float* __restrict__ out) {
  __shared__ float4 slice[NENT];           // 28 KB  [t][cl]
  __shared__ float xs[32 * 72];            // 9.2 KB [slot][cl*9+d]
  __shared__ unsigned int mask[EDIM][16];  // 512-bit row mask per species
  __shared__ int cntE[EDIM], stE[EDIM];
  __shared__ int slotB[32], slotE[32];
  __shared__ int ta3[NT3], tb3[NT3], tc3[NT3];
  __shared__ float tm3[NT3];
  __shared__ int ta2[NT2], tb2[NT2];
  __shared__ float tm2[NT2];

  const int tid = threadIdx.x;
  const int bid = blockIdx.x;
  const int rc = bid >> 4;   // row-chunk 0..15 (32 sorted rows each)
  const int ct = bid & 15;   // channel-tile 0..15 (8 channels each)
  const int cl = tid & 7;
  const int slot = tid >> 3; // 0..31
  const int c = ct * 8 + cl;

  // ---- phase 1a: zero masks ----
  if (tid < EDIM * 16) mask[tid >> 4][tid & 15] = 0u;
  __syncthreads();

  // ---- phase 1b: species masks (atomicOr is order-independent) ----
  const int r0 = tid, r1 = tid + 256;
  int e0 = 0, e1 = 0;
  for (int q = 0; q < EDIM; ++q) {
    if (y[r0 * EDIM + q] > 0.5f) e0 = q;
    if (y[r1 * EDIM + q] > 0.5f) e1 = q;
  }
  atomicOr(&mask[e0][r0 >> 5], 1u << (r0 & 31));
  atomicOr(&mask[e1][r1 >> 5], 1u << (r1 & 31));
  __syncthreads();

  if (tid < EDIM) {
    int s = 0;
    for (int w = 0; w < 16; ++w) s += __popc(mask[tid][w]);
    cntE[tid] = s;
  }
  __syncthreads();

  // ---- phase 1c: prefix (10 iters) + decode tables in parallel ----
  if (tid < EDIM) {
    int s = 0;
    for (int j = 0; j < tid; ++j) s += cntE[j];
    stE[tid] = s;
  }
  if (tid < NT3) {  // decode triple t -> (a<=b<=cc), multiplicity
    int r = tid, a = 0, b = 0;
    for (a = 0; a < DDIM; ++a) {
      int n = (DDIM - a) * (DDIM - a + 1) / 2;
      if (r < n) break;
      r -= n;
    }
    for (b = a; b < DDIM; ++b) {
      int n = DDIM - b;
      if (r < n) break;
      r -= n;
    }
    const int cc = b + r;
    ta3[tid] = a; tb3[tid] = b; tc3[tid] = cc;
    tm3[tid] = (a == b && b == cc) ? 1.f : ((a == b || b == cc) ? 3.f : 6.f);
  }
  if (tid >= 192 && tid < 192 + NT2) {  // decode pair
    int r = tid - 192, a = 0;
    for (a = 0; a < DDIM; ++a) {
      int n = DDIM - a;
      if (r < n) break;
      r -= n;
    }
    const int b = a + r;
    ta2[tid - 192] = a; tb2[tid - 192] = b;
    tm2[tid - 192] = (a == b) ? 1.f : 2.f;
  }
  __syncthreads();

  // ---- phase 1d: deterministic rank scatter into this block's window ----
  {
    const int lo = rc * 32;
#pragma unroll
    for (int k = 0; k < 2; ++k) {
      const int r = k ? r1 : r0;
      const int e = k ? e1 : e0;
      const int w = r >> 5, bit = r & 31;
      int rk = __popc(mask[e][w] & ((1u << bit) - 1u));
      for (int ww = 0; ww < w; ++ww) rk += __popc(mask[e][ww]);
      const int lp = stE[e] + rk - lo;
      if (lp >= 0 && lp < 32) { slotB[lp] = r; slotE[lp] = e; }
    }
  }
  __syncthreads();

  // ---- phase 2a: stage x for the 32 rows x 8 channels (coalesced f4) ----
  const int b = slotB[slot];
  const int myE = slotE[slot];
  {
    const float4* gb = reinterpret_cast<const float4*>(
        x + ((size_t)b * CDIM + ct * 8) * DDIM);  // byte off b*4608+ct*288 (16B aligned)
    float4* xf4 = reinterpret_cast<float4*>(&xs[0]);
    xf4[slot * 18 + cl] = gb[cl];
    xf4[slot * 18 + cl + 8] = gb[cl + 8];
    if (cl < 2) xf4[slot * 18 + cl + 16] = gb[cl + 16];
  }
  __syncthreads();

  float xv[DDIM];
#pragma unroll
  for (int d = 0; d < DDIM; ++d)
    xv[d] = xs[slot * 72 + cl * 9 + d];  // 2 lanes/bank -> free

  const int eLo = slotE[0], eHi = slotE[31];  // sorted => contiguous species range
  float a0 = 0.f, a1 = 0.f, a2 = 0.f, a3 = 0.f;

  for (int s = eLo; s <= eHi; ++s) {
    __syncthreads();  // protect slice overwrite vs previous pass readers

    // ---- phase 2b: build the 219x8 coefficient slice for species s ----
#pragma unroll
    for (int k7 = 0; k7 < 7; ++k7) {
      const int idx = tid + (k7 << 8);
      if (idx < NENT) {
        const int t = idx >> 3;
        const int c2 = ct * 8 + (idx & 7);
        float o0 = 0.f, o1 = 0.f, o2 = 0.f, o3 = 0.f;
        if (t < NT3) {
          const int a = ta3[t], bb = tb3[t], cc = tc3[t];
          const float mult = tm3[t];
          const int ub0 = ((a * DDIM + bb) * DDIM + cc) * 8;
          for (int k = 0; k < 8; ++k)
            o0 += u3_0e[ub0 + k] * w3_0e[(k * EDIM + s) * CDIM + c2];
          const int ub1 = ((a * DDIM + bb) * DDIM + cc) * 36;
          for (int k = 0; k < 12; ++k) {
            const float wv = w3_1o[(k * EDIM + s) * CDIM + c2];
            o1 += u3_1o[ub1 + k * 3 + 0] * wv;
            o2 += u3_1o[ub1 + k * 3 + 1] * wv;
            o3 += u3_1o[ub1 + k * 3 + 2] * wv;
          }
          o0 *= mult; o1 *= mult; o2 *= mult; o3 *= mult;
        } else if (t < NT3 + NT2) {
          const int q = t - NT3;
          const int a = ta2[q], bb = tb2[q];
          const float mult = tm2[q];
          const int ub0 = (a * DDIM + bb) * 3;
          for (int k = 0; k < 3; ++k)
            o0 += u2_0e[ub0 + k] * w2_0e[(k * EDIM + s) * CDIM + c2];
          const int ub1 = (a * DDIM + bb) * 12;
          for (int k = 0; k < 4; ++k) {
            const float wv = w2_1o[(k * EDIM + s) * CDIM + c2];
            o1 += u2_1o[ub1 + k * 3 + 0] * wv;
            o2 += u2_1o[ub1 + k * 3 + 1] * wv;
            o3 += u2_1o[ub1 + k * 3 + 2] * wv;
          }
          o0 *= mult; o1 *= mult; o2 *= mult; o3 *= mult;
        } else {
          const int j = t - NT3 - NT2;
          o0 = u1_0e[j] * w1_0e[s * CDIM + c2];
          const float wv = w1_1o[s * CDIM + c2];
          o1 = u1_1o[j * 3 + 0] * wv;
          o2 = u1_1o[j * 3 + 1] * wv;
          o3 = u1_1o[j * 3 + 2] * wv;
        }
        slice[idx] = make_float4(o0, o1, o2, o3);
      }
    }
    __syncthreads();

    // ---- phase 3: 219-term polynomial (only lanes of species s) ----
    if (myE == s) {
      int t = 0;
#pragma unroll
      for (int a = 0; a < DDIM; ++a) {
#pragma unroll
        for (int b2 = a; b2 < DDIM; ++b2) {
          const float xab = xv[a] * xv[b2];
#pragma unroll
          for (int c3 = b2; c3 < DDIM; ++c3) {
            const float m = xab * xv[c3];
            const float4 tv = slice[t * 8 + cl];
            a0 = fmaf(tv.x, m, a0);
            a1 = fmaf(tv.y, m, a1);
            a2 = fmaf(tv.z, m, a2);
            a3 = fmaf(tv.w, m, a3);
            ++t;
          }
        }
      }
#pragma unroll
      for (int a = 0; a < DDIM; ++a) {
#pragma unroll
        for (int b2 = a; b2 < DDIM; ++b2) {
          const float m = xv[a] * xv[b2];
          const float4 tv = slice[t * 8 + cl];
          a0 = fmaf(tv.x, m, a0);
          a1 = fmaf(tv.y, m, a1);
          a2 = fmaf(tv.z, m, a2);
          a3 = fmaf(tv.w, m, a3);
          ++t;
        }
      }
#pragma unroll
      for (int j = 0; j < DDIM; ++j) {
        const float m = xv[j];
        const float4 tv = slice[t * 8 + cl];
        a0 = fmaf(tv.x, m, a0);
        a1 = fmaf(tv.y, m, a1);
        a2 = fmaf(tv.z, m, a2);
        a3 = fmaf(tv.w, m, a3);
        ++t;
      }
    }
  }

  float4* o = reinterpret_cast<float4*>(out) + ((size_t)b * CDIM + c);
  *o = make_float4(a0, a1, a2, a3);
}

extern "C" void kernel_launch(void* const* d_in, const int* in_sizes, int n_in,
                              void* d_out, int out_size, void* d_ws, size_t ws_size,
                              hipStream_t stream) {
  const float* x     = (const float*)d_in[0];
  const float* y     = (const float*)d_in[1];
  const float* u1_0e = (const float*)d_in[2];
  const float* w1_0e = (const float*)d_in[3];
  const float* u2_0e = (const float*)d_in[4];
  const float* w2_0e = (const float*)d_in[5];
  const float* u3_0e = (const float*)d_in[6];
  const float* w3_0e = (const float*)d_in[7];
  const float* u1_1o = (const float*)d_in[8];
  const float* w1_1o = (const float*)d_in[9];
  const float* u2_1o = (const float*)d_in[10];
  const float* w2_1o = (const float*)d_in[11];
  const float* u3_1o = (const float*)d_in[12];
  const float* w3_1o = (const float*)d_in[13];

  hipLaunchKernelGGL(symcon_one_kernel, dim3(256), dim3(256), 0, stream,
                     x, y, u1_0e, w1_0e, u2_0e, w2_0e, u3_0e, w3_0e,
                     u1_1o, w1_1o, u2_1o, w2_1o, u3_1o, w3_1o,
                     (float*)d_out);
}

// Round 7
// 17.772 us; speedup vs baseline: 3.8331x; 3.8331x over previous
//
#include <hip/hip_runtime.h>

#define EDIM 10
#define CDIM 128
#define DDIM 9
#define BDIM 512
#define NT3 165   // #(a<=b<=c) triples over 9 dims
#define NT2 45    // #(a<=b) pairs
#define NT1 9
#define NT 219
#define NCH 26    // worst case sum_e ceil(n_e/32) = 512/32 + 10 = 26

// ws layout:
//   T:        [EDIM][NT][CDIM][4] float  (~4.49 MB)  (t-major, c inner: coalesced)
//   sortedB:  int[BDIM]
//   chunkE/S/C: int[NCH] each
#define TABLE_FLOATS ((size_t)EDIM * NT * CDIM * 4)

// ---------------------------------------------------------------------------
// Kernel A: blocks 0..EDIM*NT-1 build the coefficient table (one (e,t) per
// block, wave-uniform u loads, coalesced w loads + float4 store). Block
// EDIM*NT buckets rows by species and emits same-species chunks of <=32
// rows — all phases parallel (<=16 iters per species thread, no serial tail).
// ---------------------------------------------------------------------------
__global__ __launch_bounds__(CDIM) void table_bucket_kernel(
    const float* __restrict__ u1_0e, const float* __restrict__ w1_0e,
    const float* __restrict__ u2_0e, const float* __restrict__ w2_0e,
    const float* __restrict__ u3_0e, const float* __restrict__ w3_0e,
    const float* __restrict__ u1_1o, const float* __restrict__ w1_1o,
    const float* __restrict__ u2_1o, const float* __restrict__ w2_1o,
    const float* __restrict__ u3_1o, const float* __restrict__ w3_1o,
    const float* __restrict__ y,
    float* __restrict__ T, int* __restrict__ sortedB,
    int* __restrict__ chunkE, int* __restrict__ chunkS, int* __restrict__ chunkC) {
  if (blockIdx.x == EDIM * NT) {
    // ---- species bucketing: 128 threads x 4 rows each ----
    __shared__ int cnt[EDIM];
    __shared__ int st[EDIM];
    __shared__ int rk[EDIM];
    const int tid = threadIdx.x;
    if (tid < EDIM) { cnt[tid] = 0; rk[tid] = 0; }
    if (tid >= 64 && tid < 64 + NCH) chunkC[tid - 64] = 0;  // pre-zero chunks
    __syncthreads();
    int mye[4];
#pragma unroll
    for (int k = 0; k < 4; ++k) {
      const int b = tid + 128 * k;
      int e = 0;
      for (int q = 0; q < EDIM; ++q)
        if (y[b * EDIM + q] > 0.5f) e = q;
      mye[k] = e;
      atomicAdd(&cnt[e], 1);
    }
    __syncthreads();
    if (tid < EDIM) {
      int s = 0;
      for (int j = 0; j < tid; ++j) s += cnt[j];
      st[tid] = s;
    }
    __syncthreads();
    if (tid < EDIM) {
      // chunk metadata for my species (order-independent, parallel)
      int base = 0;
      for (int j = 0; j < tid; ++j) base += (cnt[j] + 31) >> 5;
      const int n = cnt[tid];
      const int nch = (n + 31) >> 5;
      for (int k = 0; k < nch; ++k) {
        chunkE[base + k] = tid;
        chunkS[base + k] = st[tid] + 32 * k;
        chunkC[base + k] = (n - 32 * k < 32) ? (n - 32 * k) : 32;
      }
    }
#pragma unroll
    for (int k = 0; k < 4; ++k) {
      const int b = tid + 128 * k;
      const int e = mye[k];
      const int r = atomicAdd(&rk[e], 1);
      sortedB[st[e] + r] = b;   // order within species irrelevant
    }
    return;
  }

  // ---- table build (round-2 verified layout/order) ----
  const int c = threadIdx.x;           // channel
  const int blk = blockIdx.x;          // e * NT + t
  const int e = blk / NT;
  const int t = blk - e * NT;

  float o0 = 0.f, o1 = 0.f, o2 = 0.f, o3 = 0.f;

  if (t < NT3) {
    int r = t, a = 0, b = 0;
    for (a = 0; a < DDIM; ++a) {
      int n = (DDIM - a) * (DDIM - a + 1) / 2;
      if (r < n) break;
      r -= n;
    }
    for (b = a; b < DDIM; ++b) {
      int n = DDIM - b;
      if (r < n) break;
      r -= n;
    }
    const int cc = b + r;
    const float mult = (a == b && b == cc) ? 1.f : ((a == b || b == cc) ? 3.f : 6.f);

    const int ub0 = ((a * DDIM + b) * DDIM + cc) * 8;       // u3_0e: (9,9,9,8,1)
    for (int k = 0; k < 8; ++k)
      o0 += u3_0e[ub0 + k] * w3_0e[(k * EDIM + e) * CDIM + c];

    const int ub1 = ((a * DDIM + b) * DDIM + cc) * 36;      // u3_1o: (9,9,9,12,3)
    for (int k = 0; k < 12; ++k) {
      const float wv = w3_1o[(k * EDIM + e) * CDIM + c];
      o1 += u3_1o[ub1 + k * 3 + 0] * wv;
      o2 += u3_1o[ub1 + k * 3 + 1] * wv;
      o3 += u3_1o[ub1 + k * 3 + 2] * wv;
    }
    o0 *= mult; o1 *= mult; o2 *= mult; o3 *= mult;
  } else if (t < NT3 + NT2) {
    int r = t - NT3, a = 0;
    for (a = 0; a < DDIM; ++a) {
      int n = DDIM - a;
      if (r < n) break;
      r -= n;
    }
    const int b = a + r;
    const float mult = (a == b) ? 1.f : 2.f;

    const int ub0 = (a * DDIM + b) * 3;                     // u2_0e: (9,9,3,1)
    for (int k = 0; k < 3; ++k)
      o0 += u2_0e[ub0 + k] * w2_0e[(k * EDIM + e) * CDIM + c];

    const int ub1 = (a * DDIM + b) * 12;                    // u2_1o: (9,9,4,3)
    for (int k = 0; k < 4; ++k) {
      const float wv = w2_1o[(k * EDIM + e) * CDIM + c];
      o1 += u2_1o[ub1 + k * 3 + 0] * wv;
      o2 += u2_1o[ub1 + k * 3 + 1] * wv;
      o3 += u2_1o[ub1 + k * 3 + 2] * wv;
    }
    o0 *= mult; o1 *= mult; o2 *= mult; o3 *= mult;
  } else {
    const int j = t - NT3 - NT2;
    o0 = u1_0e[j] * w1_0e[e * CDIM + c];                    // u1_0e: (9,1,1)
    const float wv = w1_1o[e * CDIM + c];
    o1 = u1_1o[j * 3 + 0] * wv;                             // u1_1o: (9,1,3)
    o2 = u1_1o[j * 3 + 1] * wv;
    o3 = u1_1o[j * 3 + 2] * wv;
  }

  float4* dst = reinterpret_cast<float4*>(T) + (size_t)(e * NT + t) * CDIM + c;
  *dst = make_float4(o0, o1, o2, o3);
}

// ---------------------------------------------------------------------------
// Kernel B: grid = NCH chunks x 16 channel-tiles. Block (256 thr) = 32
// same-species rows x 8 channels. Stage the 219x8 slice (28 KB) into LDS
// once (coalesced), then all 4 waves run the 219-term polynomial from LDS
// (8 unique 16 B addrs / read -> conflict-free, slot-broadcast).
// ---------------------------------------------------------------------------
__global__ __launch_bounds__(256) void symcon_main_kernel(
    const float* __restrict__ x, const float* __restrict__ T,
    const int* __restrict__ sortedB, const int* __restrict__ chunkE,
    const int* __restrict__ chunkS, const int* __restrict__ chunkC,
    float* __restrict__ out) {
  __shared__ float4 slice[NT * 8];   // 28 KB  [t][cl]
  __shared__ float xs[32 * 72];      // 9.2 KB [slot][cl*9+d]

  const int bid = blockIdx.x;
  const int chunk = bid >> 4;        // 0..NCH-1
  const int ct = bid & 15;           // channel tile (8 ch)
  const int cntc = chunkC[chunk];
  if (cntc == 0) return;
  const int e = chunkE[chunk];
  const int start = chunkS[chunk];

  const int tid = threadIdx.x;
  const int cl = tid & 7;
  const int slot = tid >> 3;         // 0..31
  const int c = ct * 8 + cl;
  const bool valid = (slot < cntc);
  const int b = sortedB[start + (valid ? slot : cntc - 1)];

  // ---- stage coefficient slice: 1752 float4, coalesced 128B groups ----
  {
    const float4* Tg = reinterpret_cast<const float4*>(T) +
                       (size_t)e * NT * CDIM + ct * 8;
#pragma unroll
    for (int k = 0; k < 7; ++k) {
      const int idx = tid + (k << 8);
      if (idx < NT * 8) {
        const int t = idx >> 3;
        const int j = idx & 7;
        slice[idx] = Tg[(size_t)t * CDIM + j];
      }
    }
  }

  // ---- stage x: slot's 8-channel strip, 18 aligned float4 ----
  {
    const float4* gb = reinterpret_cast<const float4*>(
        x + ((size_t)b * CDIM + ct * 8) * DDIM);  // byte off b*4608+ct*288 (16B aligned)
    float4* xf4 = reinterpret_cast<float4*>(&xs[0]);
    xf4[slot * 18 + cl] = gb[cl];
    xf4[slot * 18 + cl + 8] = gb[cl + 8];
    if (cl < 2) xf4[slot * 18 + cl + 16] = gb[cl + 16];
  }
  __syncthreads();

  float xv[DDIM];
#pragma unroll
  for (int d = 0; d < DDIM; ++d)
    xv[d] = xs[slot * 72 + cl * 9 + d];  // 2 lanes/bank -> free

  float a0 = 0.f, a1 = 0.f, a2 = 0.f, a3 = 0.f;
  int t = 0;

  // order 3: a<=b2<=c3 (same enumeration order as the table build)
#pragma unroll
  for (int a = 0; a < DDIM; ++a) {
#pragma unroll
    for (int b2 = a; b2 < DDIM; ++b2) {
      const float xab = xv[a] * xv[b2];
#pragma unroll
      for (int c3 = b2; c3 < DDIM; ++c3) {
        const float m = xab * xv[c3];
        const float4 tv = slice[t * 8 + cl];
        a0 = fmaf(tv.x, m, a0);
        a1 = fmaf(tv.y, m, a1);
        a2 = fmaf(tv.z, m, a2);
        a3 = fmaf(tv.w, m, a3);
        ++t;
      }
    }
  }
  // order 2
#pragma unroll
  for (int a = 0; a < DDIM; ++a) {
#pragma unroll
    for (int b2 = a; b2 < DDIM; ++b2) {
      const float m = xv[a] * xv[b2];
      const float4 tv = slice[t * 8 + cl];
      a0 = fmaf(tv.x, m, a0);
      a1 = fmaf(tv.y, m, a1);
      a2 = fmaf(tv.z, m, a2);
      a3 = fmaf(tv.w, m, a3);
      ++t;
    }
  }
  // order 1
#pragma unroll
  for (int j = 0; j < DDIM; ++j) {
    const float m = xv[j];
    const float4 tv = slice[t * 8 + cl];
    a0 = fmaf(tv.x, m, a0);
    a1 = fmaf(tv.y, m, a1);
    a2 = fmaf(tv.z, m, a2);
    a3 = fmaf(tv.w, m, a3);
    ++t;
  }

  if (valid) {
    float4* o = reinterpret_cast<float4*>(out) + ((size_t)b * CDIM + c);
    *o = make_float4(a0, a1, a2, a3);
  }
}

extern "C" void kernel_launch(void* const* d_in, const int* in_sizes, int n_in,
                              void* d_out, int out_size, void* d_ws, size_t ws_size,
                              hipStream_t stream) {
  const float* x     = (const float*)d_in[0];
  const float* y     = (const float*)d_in[1];
  const float* u1_0e = (const float*)d_in[2];
  const float* w1_0e = (const float*)d_in[3];
  const float* u2_0e = (const float*)d_in[4];
  const float* w2_0e = (const float*)d_in[5];
  const float* u3_0e = (const float*)d_in[6];
  const float* w3_0e = (const float*)d_in[7];
  const float* u1_1o = (const float*)d_in[8];
  const float* w1_1o = (const float*)d_in[9];
  const float* u2_1o = (const float*)d_in[10];
  const float* w2_1o = (const float*)d_in[11];
  const float* u3_1o = (const float*)d_in[12];
  const float* w3_1o = (const float*)d_in[13];

  float* T = (float*)d_ws;
  int* sortedB = (int*)((float*)d_ws + TABLE_FLOATS);
  int* chunkE = sortedB + BDIM;
  int* chunkS = chunkE + NCH;
  int* chunkC = chunkS + NCH;
  float* out = (float*)d_out;

  const size_t need = TABLE_FLOATS * sizeof(float) +
                      (BDIM + 3 * NCH) * sizeof(int);
  if (ws_size < need) return;

  hipLaunchKernelGGL(table_bucket_kernel, dim3(EDIM * NT + 1), dim3(CDIM), 0, stream,
                     u1_0e, w1_0e, u2_0e, w2_0e, u3_0e, w3_0e,
                     u1_1o, w1_1o, u2_1o, w2_1o, u3_1o, w3_1o,
                     y, T, sortedB, chunkE, chunkS, chunkC);

  hipLaunchKernelGGL(symcon_main_kernel, dim3(NCH * 16), dim3(256), 0, stream,
                     x, T, sortedB, chunkE, chunkS, chunkC, out);
}